// Round 7
// baseline (305.118 us; speedup 1.0000x reference)
//
#include <hip/hip_runtime.h>
#include <math.h>

#define HD 32      // hidden dim
#define FIN 64     // input features
#define NL 3       // num BernConv layers
#define NC 2       // num classes

#define TILE 8192  // edges per partition tile
#define CAP  3072  // max edges per bucket (mean ~2046, 12 sigma margin)
#define BMAX 1024  // max buckets (N <= 131072 with 128 nodes/bucket)

// clang native vectors (required by __builtin_nontemporal_*)
typedef float  f32x4 __attribute__((ext_vector_type(4)));
typedef unsigned int u32x4 __attribute__((ext_vector_type(4)));

// fast tanh; |rel err| ~1e-7, threshold 7e-2
__device__ __forceinline__ float fast_tanh(float x) {
    float e = __expf(2.0f * x);
    return 1.0f - 2.0f * __builtin_amdgcn_rcpf(e + 1.0f);
}

// fp32 -> bf16 bits, RNE
__device__ __forceinline__ unsigned int f2bf(float f) {
    unsigned int u = __float_as_uint(f);
    return (u + 0x7fffu + ((u >> 16) & 1u)) >> 16;
}
__device__ __forceinline__ unsigned int pack2(float lo, float hi) {
    return f2bf(lo) | (f2bf(hi) << 16);
}
__device__ __forceinline__ float bflo(unsigned int u) { return __uint_as_float(u << 16); }
__device__ __forceinline__ float bfhi(unsigned int u) { return __uint_as_float(u & 0xffff0000u); }

// ---------------- gcursor init ----------------
__global__ __launch_bounds__(256) void init_kernel(int* __restrict__ gcursor, int B) {
    int b = blockIdx.x * 256 + threadIdx.x;
    if (b < B) gcursor[b] = b * CAP;
}

// ---------------- LDS-staged partition: bucket edges by dst>>7 ----------------
__global__ __launch_bounds__(256) void partition_kernel(const int* __restrict__ src,
                                                        const int* __restrict__ dst,
                                                        int* __restrict__ gcursor,
                                                        unsigned int* __restrict__ bucket_buf,
                                                        int E) {
    __shared__ unsigned int vals[TILE];
    __shared__ unsigned short bid[TILE];
    __shared__ int hist[BMAX];
    __shared__ int lcur[BMAX];
    __shared__ int goff[BMAX];
    __shared__ int sc[256];
    int t = threadIdx.x;
    int tile_base = blockIdx.x * TILE;
    int n_tile = min(TILE, E - tile_base);

    for (int i = t; i < BMAX; i += 256) hist[i] = 0;
    __syncthreads();

    unsigned int pk[TILE / 256];
    int bk[TILE / 256];
#pragma unroll
    for (int k = 0; k < TILE / 256; ++k) {
        int e = tile_base + k * 256 + t;
        if (e < E) {
            int s = src[e], d = dst[e];
            int b = d >> 7;
            pk[k] = ((unsigned)s << 7) | (unsigned)(d & 127);
            bk[k] = b;
            atomicAdd(&hist[b], 1);
        } else bk[k] = -1;
    }
    __syncthreads();

    int base4 = t * 4;
    int sum4 = hist[base4] + hist[base4 + 1] + hist[base4 + 2] + hist[base4 + 3];
    sc[t] = sum4;
    __syncthreads();
    for (int off = 1; off < 256; off <<= 1) {
        int v = (t >= off) ? sc[t - off] : 0;
        __syncthreads();
        sc[t] += v;
        __syncthreads();
    }
    int run = sc[t] - sum4;
#pragma unroll
    for (int j = 0; j < 4; ++j) {
        int tmp = hist[base4 + j];
        hist[base4 + j] = run;
        lcur[base4 + j] = run;
        run += tmp;
    }
    __syncthreads();

#pragma unroll
    for (int k = 0; k < TILE / 256; ++k) {
        if (bk[k] >= 0) {
            int pos = atomicAdd(&lcur[bk[k]], 1);
            vals[pos] = pk[k];
            bid[pos] = (unsigned short)bk[k];
        }
    }
    __syncthreads();

    for (int b = t; b < BMAX; b += 256) {
        int cnt = lcur[b] - hist[b];
        goff[b] = (cnt > 0) ? atomicAdd(&gcursor[b], cnt) : 0;
    }
    __syncthreads();

    for (int i = t; i < n_tile; i += 256) {
        int b = bid[i];
        int addr = goff[b] + (i - hist[b]);
        if (addr < (b + 1) * CAP)
            bucket_buf[addr] = vals[i];
    }
}

// ---------------- per-bucket CSR build (in place) ----------------
__global__ __launch_bounds__(256) void bucket_csr_kernel(unsigned int* bucket_buf,
                                                         const int* __restrict__ gcursor,
                                                         int* __restrict__ row_start,
                                                         int* __restrict__ degA,
                                                         float* __restrict__ dinv,
                                                         int N) {
    __shared__ int ldeg[128], lexc[128], lcur2[128];
    __shared__ int colLDS[CAP];
    int b = blockIdx.x;
    int t = threadIdx.x;
    int base = b * CAP;
    int cnt = min(gcursor[b] - base, CAP);

    if (t < 128) ldeg[t] = 0;
    __syncthreads();
    for (int i = t; i < cnt; i += 256)
        atomicAdd(&ldeg[bucket_buf[base + i] & 127], 1);
    __syncthreads();

    if (t < 128) lexc[t] = ldeg[t];
    __syncthreads();
    for (int off = 1; off < 128; off <<= 1) {
        int v = (t >= off && t < 128) ? lexc[t - off] : 0;
        __syncthreads();
        if (t < 128) lexc[t] += v;
        __syncthreads();
    }
    if (t < 128) {
        int ex = lexc[t] - ldeg[t];
        lcur2[t] = ex;
        int node = (b << 7) + t;
        if (node < N) {
            row_start[node] = base + ex;
            degA[node] = ldeg[t];
            dinv[node] = rsqrtf(fmaxf((float)ldeg[t], 1.0f));
        }
    }
    __syncthreads();

    for (int i = t; i < cnt; i += 256) {
        unsigned int v = bucket_buf[base + i];
        int pos = atomicAdd(&lcur2[(int)(v & 127)], 1);
        colLDS[pos] = (int)(v >> 7);
    }
    __syncthreads();
    for (int i = t; i < cnt; i += 256)
        bucket_buf[base + i] = (unsigned int)colLDS[i];   // now = col[]
}

// ---------------- MLP in: h = relu(feat@W1+b1)@W2+b2 ----------------
// Emits fp32 half-planes h_lo/h_hi (N x 16) and bf16 scaled tables
// hs_lo/hs_hi (N x 16 bf16 = 32B rows; 3.2 MB — fits per-XCD L2).
__global__ __launch_bounds__(256) void mlp_kernel(const float* __restrict__ feat,
                                                  const float* __restrict__ W1,
                                                  const float* __restrict__ b1,
                                                  const float* __restrict__ W2,
                                                  const float* __restrict__ b2,
                                                  const float* __restrict__ dinv,
                                                  float* __restrict__ h_lo,
                                                  float* __restrict__ h_hi,
                                                  u32x4* __restrict__ hs_lo,
                                                  u32x4* __restrict__ hs_hi, int N) {
    int n = blockIdx.x * 256 + threadIdx.x;
    if (n >= N) return;

    float h1[HD];
#pragma unroll
    for (int j = 0; j < HD; ++j) h1[j] = b1[j];
    const f32x4* fp = (const f32x4*)feat;
#pragma unroll
    for (int k4 = 0; k4 < FIN / 4; ++k4) {
        f32x4 v = fp[(size_t)n * (FIN / 4) + k4];
        const float* w = &W1[k4 * 4 * HD];
#pragma unroll
        for (int j = 0; j < HD; ++j)
            h1[j] = fmaf(v.w, w[3 * HD + j],
                    fmaf(v.z, w[2 * HD + j],
                    fmaf(v.y, w[1 * HD + j],
                    fmaf(v.x, w[0 * HD + j], h1[j]))));
    }
    float h2[HD];
#pragma unroll
    for (int j = 0; j < HD; ++j) h2[j] = b2[j];
#pragma unroll
    for (int k = 0; k < HD; ++k) {
        float a = fmaxf(h1[k], 0.0f);
#pragma unroll
        for (int j = 0; j < HD; ++j) h2[j] = fmaf(a, W2[k * HD + j], h2[j]);
    }

    f32x4* lo4 = (f32x4*)h_lo;
    f32x4* hi4 = (f32x4*)h_hi;
#pragma unroll
    for (int q = 0; q < 4; ++q) {
        f32x4 a = {h2[4 * q], h2[4 * q + 1], h2[4 * q + 2], h2[4 * q + 3]};
        f32x4 b = {h2[16 + 4 * q], h2[16 + 4 * q + 1], h2[16 + 4 * q + 2], h2[16 + 4 * q + 3]};
        __builtin_nontemporal_store(a, &lo4[(size_t)n * 4 + q]);
        __builtin_nontemporal_store(b, &hi4[(size_t)n * 4 + q]);
    }
    float di = dinv[n];
#pragma unroll
    for (int q = 0; q < 2; ++q) {   // q=0: feats 0..7 / 16..23 ; q=1: 8..15 / 24..31
        u32x4 u, v;
        u.x = pack2(di * h2[8 * q + 0], di * h2[8 * q + 1]);
        u.y = pack2(di * h2[8 * q + 2], di * h2[8 * q + 3]);
        u.z = pack2(di * h2[8 * q + 4], di * h2[8 * q + 5]);
        u.w = pack2(di * h2[8 * q + 6], di * h2[8 * q + 7]);
        v.x = pack2(di * h2[16 + 8 * q + 0], di * h2[16 + 8 * q + 1]);
        v.y = pack2(di * h2[16 + 8 * q + 2], di * h2[16 + 8 * q + 3]);
        v.z = pack2(di * h2[16 + 8 * q + 4], di * h2[16 + 8 * q + 5]);
        v.w = pack2(di * h2[16 + 8 * q + 6], di * h2[16 + 8 * q + 7]);
        hs_lo[(size_t)n * 2 + q] = u;
        hs_hi[(size_t)n * 2 + q] = v;
    }
}

// ---------------- gather #1 (half): acc = sum hs[col]; s0 = acc;
//                  f1s = bf16(d*(h + d*acc)) — 2 lanes/node ----------------
__global__ __launch_bounds__(256) void gather1_half_kernel(const float* __restrict__ h_half,
                                                           const u32x4* __restrict__ hs_half,
                                                           const float* __restrict__ dinv,
                                                           const int* __restrict__ row_start,
                                                           const int* __restrict__ deg,
                                                           const int* __restrict__ col,
                                                           float* __restrict__ s0_half,
                                                           u32x4* __restrict__ f1s_half, int N) {
    int t = blockIdx.x * 256 + threadIdx.x;
    int n = t >> 1;
    if (n >= N) return;
    int q = t & 1;
    int s = row_start[n];
    int e_end = s + deg[n];
    float acc[8] = {0.f, 0.f, 0.f, 0.f, 0.f, 0.f, 0.f, 0.f};
    for (int e = s; e < e_end; ++e) {
        int c = __builtin_nontemporal_load(&col[e]);
        u32x4 v = hs_half[(size_t)c * 2 + q];
        acc[0] += bflo(v.x); acc[1] += bfhi(v.x);
        acc[2] += bflo(v.y); acc[3] += bfhi(v.y);
        acc[4] += bflo(v.z); acc[5] += bfhi(v.z);
        acc[6] += bflo(v.w); acc[7] += bfhi(v.w);
    }
    float di = dinv[n];
    const f32x4* h4 = (const f32x4*)h_half;
    f32x4 ha = __builtin_nontemporal_load(&h4[(size_t)n * 4 + 2 * q]);
    f32x4 hb = __builtin_nontemporal_load(&h4[(size_t)n * 4 + 2 * q + 1]);
    float f[8] = {fmaf(di, acc[0], ha.x), fmaf(di, acc[1], ha.y),
                  fmaf(di, acc[2], ha.z), fmaf(di, acc[3], ha.w),
                  fmaf(di, acc[4], hb.x), fmaf(di, acc[5], hb.y),
                  fmaf(di, acc[6], hb.z), fmaf(di, acc[7], hb.w)};
    f32x4 sa = {acc[0], acc[1], acc[2], acc[3]};
    f32x4 sb = {acc[4], acc[5], acc[6], acc[7]};
    __builtin_nontemporal_store(sa, &((f32x4*)s0_half)[(size_t)n * 4 + 2 * q]);
    __builtin_nontemporal_store(sb, &((f32x4*)s0_half)[(size_t)n * 4 + 2 * q + 1]);
    u32x4 u;
    u.x = pack2(di * f[0], di * f[1]);
    u.y = pack2(di * f[2], di * f[3]);
    u.z = pack2(di * f[4], di * f[5]);
    u.w = pack2(di * f[6], di * f[7]);
    f1s_half[(size_t)n * 2 + q] = u;     // keep in L2 — next kernel's table
}

// ---------------- gather #2 (half): t1 = sum f1s[col] ----------------
__global__ __launch_bounds__(256) void gather2_half_kernel(const u32x4* __restrict__ f1s_half,
                                                           const int* __restrict__ row_start,
                                                           const int* __restrict__ deg,
                                                           const int* __restrict__ col,
                                                           float* __restrict__ t1_half, int N) {
    int t = blockIdx.x * 256 + threadIdx.x;
    int n = t >> 1;
    if (n >= N) return;
    int q = t & 1;
    int s = row_start[n];
    int e_end = s + deg[n];
    float acc[8] = {0.f, 0.f, 0.f, 0.f, 0.f, 0.f, 0.f, 0.f};
    for (int e = s; e < e_end; ++e) {
        int c = __builtin_nontemporal_load(&col[e]);
        u32x4 v = f1s_half[(size_t)c * 2 + q];
        acc[0] += bflo(v.x); acc[1] += bfhi(v.x);
        acc[2] += bflo(v.y); acc[3] += bfhi(v.y);
        acc[4] += bflo(v.z); acc[5] += bfhi(v.z);
        acc[6] += bflo(v.w); acc[7] += bfhi(v.w);
    }
    f32x4 sa = {acc[0], acc[1], acc[2], acc[3]};
    f32x4 sb = {acc[4], acc[5], acc[6], acc[7]};
    __builtin_nontemporal_store(sa, &((f32x4*)t1_half)[(size_t)n * 4 + 2 * q]);
    __builtin_nontemporal_store(sb, &((f32x4*)t1_half)[(size_t)n * 4 + 2 * q + 1]);
}

// ---------------- fused epilogue ----------------
// Bases: f2 = h + d*s0 + d*t1; g1 = h + d*s0 - d*t1; g2 = h - 3d*s0 + d*t1
__global__ __launch_bounds__(256) void final_kernel(const float* __restrict__ h_lo,
                                                    const float* __restrict__ h_hi,
                                                    const float* __restrict__ s0_lo,
                                                    const float* __restrict__ s0_hi,
                                                    const float* __restrict__ t1_lo,
                                                    const float* __restrict__ t1_hi,
                                                    const float* __restrict__ dinv,
                                                    const float* __restrict__ W2,
                                                    const float* __restrict__ b2,
                                                    const float* __restrict__ Wc,
                                                    const float* __restrict__ bc,
                                                    const float* __restrict__ wbern,
                                                    float* __restrict__ out, int N) {
    int n = blockIdx.x * 256 + threadIdx.x;
    if (n >= N) return;
    float di = dinv[n];

    // load half-planes into full-row registers
    float hv[HD], sv[HD], tv[HD];
    {
        const f32x4* a = (const f32x4*)h_lo;  const f32x4* b = (const f32x4*)h_hi;
        const f32x4* c = (const f32x4*)s0_lo; const f32x4* d = (const f32x4*)s0_hi;
        const f32x4* e = (const f32x4*)t1_lo; const f32x4* f = (const f32x4*)t1_hi;
#pragma unroll
        for (int q = 0; q < 4; ++q) {
            f32x4 v;
            v = a[(size_t)n * 4 + q]; hv[4*q]=v.x; hv[4*q+1]=v.y; hv[4*q+2]=v.z; hv[4*q+3]=v.w;
            v = b[(size_t)n * 4 + q]; hv[16+4*q]=v.x; hv[16+4*q+1]=v.y; hv[16+4*q+2]=v.z; hv[16+4*q+3]=v.w;
            v = c[(size_t)n * 4 + q]; sv[4*q]=v.x; sv[4*q+1]=v.y; sv[4*q+2]=v.z; sv[4*q+3]=v.w;
            v = d[(size_t)n * 4 + q]; sv[16+4*q]=v.x; sv[16+4*q+1]=v.y; sv[16+4*q+2]=v.z; sv[16+4*q+3]=v.w;
            v = e[(size_t)n * 4 + q]; tv[4*q]=v.x; tv[4*q+1]=v.y; tv[4*q+2]=v.z; tv[4*q+3]=v.w;
            v = f[(size_t)n * 4 + q]; tv[16+4*q]=v.x; tv[16+4*q+1]=v.y; tv[16+4*q+2]=v.z; tv[16+4*q+3]=v.w;
        }
    }

    // xp = tanh(h@W2 + b2)
    float xp[HD];
#pragma unroll
    for (int j = 0; j < HD; ++j) xp[j] = b2[j];
#pragma unroll
    for (int k = 0; k < HD; ++k) {
        float a = hv[k];
        const float* w = &W2[k * HD];
#pragma unroll
        for (int j = 0; j < HD; ++j) xp[j] = fmaf(a, w[j], xp[j]);
    }
#pragma unroll
    for (int j = 0; j < HD; ++j) xp[j] = fast_tanh(xp[j]);

    float uf[HD], ug[HD], uh[HD];
#pragma unroll
    for (int j = 0; j < HD; ++j) { uf[j] = 0.f; ug[j] = 0.f; uh[j] = 0.f; }
    float vf0 = 0.f, vf1 = 0.f, vg0 = 0.f, vg1 = 0.f, vh0 = 0.f, vh1 = 0.f;
#pragma unroll
    for (int k = 0; k < HD; ++k) {
        float da = di * sv[k];
        float db = di * tv[k];
        float f2k = hv[k] + da + db;
        float g1k = hv[k] + da - db;
        float g2k = hv[k] - 3.0f * da + db;
        const float* w = &W2[k * HD];
#pragma unroll
        for (int j = 0; j < HD; ++j) {
            uf[j] = fmaf(f2k, w[j], uf[j]);
            ug[j] = fmaf(g1k, w[j], ug[j]);
            uh[j] = fmaf(g2k, w[j], uh[j]);
        }
        vf0 = fmaf(f2k, Wc[k * NC + 0], vf0);
        vf1 = fmaf(f2k, Wc[k * NC + 1], vf1);
        vg0 = fmaf(g1k, Wc[k * NC + 0], vg0);
        vg1 = fmaf(g1k, Wc[k * NC + 1], vg1);
        vh0 = fmaf(g2k, Wc[k * NC + 0], vh0);
        vh1 = fmaf(g2k, Wc[k * NC + 1], vh1);
    }

    float logits[NL];
#pragma unroll
    for (int i = 0; i < NL; ++i) {
        float wa = 0.25f * fmaxf(wbern[i * 3 + 0], 0.0f);
        float wb = 0.50f * fmaxf(wbern[i * 3 + 1], 0.0f);
        float wc = 0.25f * fmaxf(wbern[i * 3 + 2], 0.0f);
        float lg = 0.0f;
#pragma unroll
        for (int j = 0; j < HD; ++j) {
            float p = fmaf(wa, uf[j], fmaf(wb, ug[j], fmaf(wc, uh[j], b2[j])));
            lg = fmaf(fast_tanh(p), xp[j], lg);
        }
        logits[i] = lg;
    }

    float m = fmaxf(logits[0], fmaxf(logits[1], logits[2]));
    float e0 = __expf(logits[0] - m), e1 = __expf(logits[1] - m), e2 = __expf(logits[2] - m);
    float inv = 1.0f / (e0 + e1 + e2);
    float scs[NL] = {e0 * inv, e1 * inv, e2 * inv};

    float A = 0.0f, B = 0.0f, Cc = 0.0f;
#pragma unroll
    for (int i = 0; i < NL; ++i) {
        A  += scs[i] * 0.25f * fmaxf(wbern[i * 3 + 0], 0.0f);
        B  += scs[i] * 0.50f * fmaxf(wbern[i * 3 + 1], 0.0f);
        Cc += scs[i] * 0.25f * fmaxf(wbern[i * 3 + 2], 0.0f);
    }
    out[(size_t)n * NC + 0] = bc[0] + A * vf0 + B * vg0 + Cc * vh0;
    out[(size_t)n * NC + 1] = bc[1] + A * vf1 + B * vg1 + Cc * vh1;
}

extern "C" void kernel_launch(void* const* d_in, const int* in_sizes, int n_in,
                              void* d_out, int out_size, void* d_ws, size_t ws_size,
                              hipStream_t stream) {
    const float* feature = (const float*)d_in[0];
    const float* W1 = (const float*)d_in[1];
    const float* b1 = (const float*)d_in[2];
    const float* W2 = (const float*)d_in[3];
    const float* b2 = (const float*)d_in[4];
    const float* Wc = (const float*)d_in[5];
    const float* bc = (const float*)d_in[6];
    const float* wbern = (const float*)d_in[7];
    const int* src = (const int*)d_in[8];
    const int* dst = (const int*)d_in[9];

    const int N = in_sizes[0] / FIN;   // 100000
    const int E = in_sizes[8];         // 1600000
    const int B = (N + 127) >> 7;      // 782 buckets

    // workspace layout
    char* p = (char*)d_ws;
    size_t Np = ((size_t)N + 255) & ~(size_t)255;
    size_t N16 = (size_t)N * 16;
    int* gcursor   = (int*)p;              p += ((size_t)BMAX) * 4;
    int* row_start = (int*)p;              p += Np * 4;
    int* degA      = (int*)p;              p += Np * 4;
    float* dinv    = (float*)p;            p += Np * 4;
    unsigned int* bucket_buf = (unsigned int*)p;  p += (size_t)B * CAP * 4;  // becomes col[]
    float* h_lo  = (float*)p;              p += N16 * 4;
    float* h_hi  = (float*)p;              p += N16 * 4;
    float* s0_lo = (float*)p;              p += N16 * 4;
    float* s0_hi = (float*)p;              p += N16 * 4;
    float* t1_lo = (float*)p;              p += N16 * 4;
    float* t1_hi = (float*)p;              p += N16 * 4;
    u32x4* hs_lo  = (u32x4*)p;             p += N16 * 2;  // 3.2 MB — fits XCD L2
    u32x4* hs_hi  = (u32x4*)p;             p += N16 * 2;
    u32x4* f1s_lo = (u32x4*)p;             p += N16 * 2;
    u32x4* f1s_hi = (u32x4*)p;             p += N16 * 2;

    int bN = (N + 255) / 256;
    int bG = ((N * 2) + 255) / 256;
    int nTiles = (E + TILE - 1) / TILE;

    init_kernel<<<(B + 255) / 256, 256, 0, stream>>>(gcursor, B);
    partition_kernel<<<nTiles, 256, 0, stream>>>(src, dst, gcursor, bucket_buf, E);
    bucket_csr_kernel<<<B, 256, 0, stream>>>(bucket_buf, gcursor, row_start, degA, dinv, N);

    mlp_kernel<<<bN, 256, 0, stream>>>(feature, W1, b1, W2, b2, dinv,
                                       h_lo, h_hi, hs_lo, hs_hi, N);

    const int* col = (const int*)bucket_buf;
    // lo chain, then hi chain — each keeps a single 3.2 MB table hot in L2
    gather1_half_kernel<<<bG, 256, 0, stream>>>(h_lo, hs_lo, dinv, row_start, degA, col,
                                                s0_lo, f1s_lo, N);
    gather2_half_kernel<<<bG, 256, 0, stream>>>(f1s_lo, row_start, degA, col, t1_lo, N);
    gather1_half_kernel<<<bG, 256, 0, stream>>>(h_hi, hs_hi, dinv, row_start, degA, col,
                                                s0_hi, f1s_hi, N);
    gather2_half_kernel<<<bG, 256, 0, stream>>>(f1s_hi, row_start, degA, col, t1_hi, N);

    final_kernel<<<bN, 256, 0, stream>>>(h_lo, h_hi, s0_lo, s0_hi, t1_lo, t1_hi,
                                         dinv, W2, b2, Wc, bc, wbern, (float*)d_out, N);
}

// Round 8
// 252.443 us; speedup vs baseline: 1.2087x; 1.2087x over previous
//
#include <hip/hip_runtime.h>
#include <math.h>

#define HD 32      // hidden dim
#define FIN 64     // input features
#define NL 3       // num BernConv layers
#define NC 2       // num classes

#define TILE 8192  // edges per partition tile
#define CAP  3072  // max edges per bucket (mean ~2046, 12 sigma margin)
#define BMAX 1024  // max buckets (N <= 131072 with 128 nodes/bucket)

// clang native vectors (required by __builtin_nontemporal_*)
typedef float  f32x4 __attribute__((ext_vector_type(4)));
typedef unsigned int u32x4 __attribute__((ext_vector_type(4)));

// fast tanh; |rel err| ~1e-7, threshold 7e-2
__device__ __forceinline__ float fast_tanh(float x) {
    float e = __expf(2.0f * x);
    return 1.0f - 2.0f * __builtin_amdgcn_rcpf(e + 1.0f);
}

// fp32 -> bf16 bits, RNE
__device__ __forceinline__ unsigned int f2bf(float f) {
    unsigned int u = __float_as_uint(f);
    return (u + 0x7fffu + ((u >> 16) & 1u)) >> 16;
}
__device__ __forceinline__ unsigned int pack2(float lo, float hi) {
    return f2bf(lo) | (f2bf(hi) << 16);
}
__device__ __forceinline__ float bflo(unsigned int u) { return __uint_as_float(u << 16); }
__device__ __forceinline__ float bfhi(unsigned int u) { return __uint_as_float(u & 0xffff0000u); }

// ---------------- gcursor init ----------------
__global__ __launch_bounds__(256) void init_kernel(int* __restrict__ gcursor, int B) {
    int b = blockIdx.x * 256 + threadIdx.x;
    if (b < B) gcursor[b] = b * CAP;
}

// ---------------- LDS-staged partition: bucket edges by dst>>7 ----------------
__global__ __launch_bounds__(256) void partition_kernel(const int* __restrict__ src,
                                                        const int* __restrict__ dst,
                                                        int* __restrict__ gcursor,
                                                        unsigned int* __restrict__ bucket_buf,
                                                        int E) {
    __shared__ unsigned int vals[TILE];
    __shared__ unsigned short bid[TILE];
    __shared__ int hist[BMAX];
    __shared__ int lcur[BMAX];
    __shared__ int goff[BMAX];
    __shared__ int sc[256];
    int t = threadIdx.x;
    int tile_base = blockIdx.x * TILE;
    int n_tile = min(TILE, E - tile_base);

    for (int i = t; i < BMAX; i += 256) hist[i] = 0;
    __syncthreads();

    unsigned int pk[TILE / 256];
    int bk[TILE / 256];
#pragma unroll
    for (int k = 0; k < TILE / 256; ++k) {
        int e = tile_base + k * 256 + t;
        if (e < E) {
            int s = src[e], d = dst[e];
            int b = d >> 7;
            pk[k] = ((unsigned)s << 7) | (unsigned)(d & 127);
            bk[k] = b;
            atomicAdd(&hist[b], 1);
        } else bk[k] = -1;
    }
    __syncthreads();

    int base4 = t * 4;
    int sum4 = hist[base4] + hist[base4 + 1] + hist[base4 + 2] + hist[base4 + 3];
    sc[t] = sum4;
    __syncthreads();
    for (int off = 1; off < 256; off <<= 1) {
        int v = (t >= off) ? sc[t - off] : 0;
        __syncthreads();
        sc[t] += v;
        __syncthreads();
    }
    int run = sc[t] - sum4;
#pragma unroll
    for (int j = 0; j < 4; ++j) {
        int tmp = hist[base4 + j];
        hist[base4 + j] = run;
        lcur[base4 + j] = run;
        run += tmp;
    }
    __syncthreads();

#pragma unroll
    for (int k = 0; k < TILE / 256; ++k) {
        if (bk[k] >= 0) {
            int pos = atomicAdd(&lcur[bk[k]], 1);
            vals[pos] = pk[k];
            bid[pos] = (unsigned short)bk[k];
        }
    }
    __syncthreads();

    for (int b = t; b < BMAX; b += 256) {
        int cnt = lcur[b] - hist[b];
        goff[b] = (cnt > 0) ? atomicAdd(&gcursor[b], cnt) : 0;
    }
    __syncthreads();

    for (int i = t; i < n_tile; i += 256) {
        int b = bid[i];
        int addr = goff[b] + (i - hist[b]);
        if (addr < (b + 1) * CAP)
            bucket_buf[addr] = vals[i];
    }
}

// ---------------- per-bucket CSR build (in place) ----------------
__global__ __launch_bounds__(256) void bucket_csr_kernel(unsigned int* bucket_buf,
                                                         const int* __restrict__ gcursor,
                                                         int* __restrict__ row_start,
                                                         int* __restrict__ degA,
                                                         float* __restrict__ dinv,
                                                         int N) {
    __shared__ int ldeg[128], lexc[128], lcur2[128];
    __shared__ int colLDS[CAP];
    int b = blockIdx.x;
    int t = threadIdx.x;
    int base = b * CAP;
    int cnt = min(gcursor[b] - base, CAP);

    if (t < 128) ldeg[t] = 0;
    __syncthreads();
    for (int i = t; i < cnt; i += 256)
        atomicAdd(&ldeg[bucket_buf[base + i] & 127], 1);
    __syncthreads();

    if (t < 128) lexc[t] = ldeg[t];
    __syncthreads();
    for (int off = 1; off < 128; off <<= 1) {
        int v = (t >= off && t < 128) ? lexc[t - off] : 0;
        __syncthreads();
        if (t < 128) lexc[t] += v;
        __syncthreads();
    }
    if (t < 128) {
        int ex = lexc[t] - ldeg[t];
        lcur2[t] = ex;
        int node = (b << 7) + t;
        if (node < N) {
            row_start[node] = base + ex;
            degA[node] = ldeg[t];
            dinv[node] = rsqrtf(fmaxf((float)ldeg[t], 1.0f));
        }
    }
    __syncthreads();

    for (int i = t; i < cnt; i += 256) {
        unsigned int v = bucket_buf[base + i];
        int pos = atomicAdd(&lcur2[(int)(v & 127)], 1);
        colLDS[pos] = (int)(v >> 7);
    }
    __syncthreads();
    for (int i = t; i < cnt; i += 256)
        bucket_buf[base + i] = (unsigned int)colLDS[i];   // now = col[]
}

// ---------------- MLP in: h = relu(feat@W1+b1)@W2+b2 ----------------
// Emits h (N x 32 fp32, streamed NT) and hs (N x 32 bf16 * dinv — the 64B
// gather table, cacheable).
__global__ __launch_bounds__(256) void mlp_kernel(const float* __restrict__ feat,
                                                  const float* __restrict__ W1,
                                                  const float* __restrict__ b1,
                                                  const float* __restrict__ W2,
                                                  const float* __restrict__ b2,
                                                  const float* __restrict__ dinv,
                                                  float* __restrict__ hout,
                                                  u32x4* __restrict__ hs, int N) {
    int n = blockIdx.x * 256 + threadIdx.x;
    if (n >= N) return;

    float h1[HD];
#pragma unroll
    for (int j = 0; j < HD; ++j) h1[j] = b1[j];
    const f32x4* fp = (const f32x4*)feat;
#pragma unroll
    for (int k4 = 0; k4 < FIN / 4; ++k4) {
        f32x4 v = fp[(size_t)n * (FIN / 4) + k4];
        const float* w = &W1[k4 * 4 * HD];
#pragma unroll
        for (int j = 0; j < HD; ++j)
            h1[j] = fmaf(v.w, w[3 * HD + j],
                    fmaf(v.z, w[2 * HD + j],
                    fmaf(v.y, w[1 * HD + j],
                    fmaf(v.x, w[0 * HD + j], h1[j]))));
    }
    float h2[HD];
#pragma unroll
    for (int j = 0; j < HD; ++j) h2[j] = b2[j];
#pragma unroll
    for (int k = 0; k < HD; ++k) {
        float a = fmaxf(h1[k], 0.0f);
#pragma unroll
        for (int j = 0; j < HD; ++j) h2[j] = fmaf(a, W2[k * HD + j], h2[j]);
    }

    f32x4* op = (f32x4*)hout;
#pragma unroll
    for (int q = 0; q < HD / 4; ++q) {
        f32x4 v = {h2[4 * q], h2[4 * q + 1], h2[4 * q + 2], h2[4 * q + 3]};
        __builtin_nontemporal_store(v, &op[(size_t)n * 8 + q]);
    }
    float di = dinv[n];
#pragma unroll
    for (int q = 0; q < 4; ++q) {   // quad q covers feats [8q, 8q+8)
        u32x4 u;
        u.x = pack2(di * h2[8 * q + 0], di * h2[8 * q + 1]);
        u.y = pack2(di * h2[8 * q + 2], di * h2[8 * q + 3]);
        u.z = pack2(di * h2[8 * q + 4], di * h2[8 * q + 5]);
        u.w = pack2(di * h2[8 * q + 6], di * h2[8 * q + 7]);
        hs[(size_t)n * 4 + q] = u;
    }
}

// ---------------- gather #1: acc = sum hs[col]; s0 = acc (fp32);
//                  f1s = bf16(d*(h + d*acc)) ----------------
// 8 lanes/node: 4 feature-quads x 2 edge-parity walks; shfl_xor(4) combine.
__global__ __launch_bounds__(256) void gather1_kernel(const float* __restrict__ h,
                                                      const u32x4* __restrict__ hs,
                                                      const float* __restrict__ dinv,
                                                      const int* __restrict__ row_start,
                                                      const int* __restrict__ deg,
                                                      const int* __restrict__ col,
                                                      float* __restrict__ s0,
                                                      u32x4* __restrict__ f1s, int N) {
    int t = blockIdx.x * 256 + threadIdx.x;
    int n = t >> 3;
    if (n >= N) return;
    int sub = t & 7;
    int qf = sub & 3;       // feature quad
    int eh = sub >> 2;      // edge parity
    int s = row_start[n];
    int e_end = s + deg[n];
    float acc[8] = {0.f, 0.f, 0.f, 0.f, 0.f, 0.f, 0.f, 0.f};
    for (int e = s + eh; e < e_end; e += 2) {
        int c = col[e];
        u32x4 v = hs[(size_t)c * 4 + qf];
        acc[0] += bflo(v.x); acc[1] += bfhi(v.x);
        acc[2] += bflo(v.y); acc[3] += bfhi(v.y);
        acc[4] += bflo(v.z); acc[5] += bfhi(v.z);
        acc[6] += bflo(v.w); acc[7] += bfhi(v.w);
    }
#pragma unroll
    for (int i = 0; i < 8; ++i) acc[i] += __shfl_xor(acc[i], 4);

    float di = dinv[n];
    f32x4* s04 = (f32x4*)s0;
    if (eh == 0) {
        f32x4 sa = {acc[0], acc[1], acc[2], acc[3]};
        __builtin_nontemporal_store(sa, &s04[(size_t)n * 8 + 2 * qf]);
    } else {
        f32x4 sb = {acc[4], acc[5], acc[6], acc[7]};
        __builtin_nontemporal_store(sb, &s04[(size_t)n * 8 + 2 * qf + 1]);
        const f32x4* h4 = (const f32x4*)h;
        f32x4 ha = __builtin_nontemporal_load(&h4[(size_t)n * 8 + 2 * qf]);
        f32x4 hb = __builtin_nontemporal_load(&h4[(size_t)n * 8 + 2 * qf + 1]);
        u32x4 u;
        u.x = pack2(di * fmaf(di, acc[0], ha.x), di * fmaf(di, acc[1], ha.y));
        u.y = pack2(di * fmaf(di, acc[2], ha.z), di * fmaf(di, acc[3], ha.w));
        u.z = pack2(di * fmaf(di, acc[4], hb.x), di * fmaf(di, acc[5], hb.y));
        u.w = pack2(di * fmaf(di, acc[6], hb.z), di * fmaf(di, acc[7], hb.w));
        f1s[(size_t)n * 4 + qf] = u;    // cacheable — next kernel's gather table
    }
}

// ---------------- gather #2: t1 = sum f1s[col] ----------------
__global__ __launch_bounds__(256) void gather2_kernel(const u32x4* __restrict__ f1s,
                                                      const int* __restrict__ row_start,
                                                      const int* __restrict__ deg,
                                                      const int* __restrict__ col,
                                                      float* __restrict__ t1, int N) {
    int t = blockIdx.x * 256 + threadIdx.x;
    int n = t >> 3;
    if (n >= N) return;
    int sub = t & 7;
    int qf = sub & 3;
    int eh = sub >> 2;
    int s = row_start[n];
    int e_end = s + deg[n];
    float acc[8] = {0.f, 0.f, 0.f, 0.f, 0.f, 0.f, 0.f, 0.f};
    for (int e = s + eh; e < e_end; e += 2) {
        int c = col[e];
        u32x4 v = f1s[(size_t)c * 4 + qf];
        acc[0] += bflo(v.x); acc[1] += bfhi(v.x);
        acc[2] += bflo(v.y); acc[3] += bfhi(v.y);
        acc[4] += bflo(v.z); acc[5] += bfhi(v.z);
        acc[6] += bflo(v.w); acc[7] += bfhi(v.w);
    }
#pragma unroll
    for (int i = 0; i < 8; ++i) acc[i] += __shfl_xor(acc[i], 4);

    f32x4* t14 = (f32x4*)t1;
    if (eh == 0) {
        f32x4 sa = {acc[0], acc[1], acc[2], acc[3]};
        __builtin_nontemporal_store(sa, &t14[(size_t)n * 8 + 2 * qf]);
    } else {
        f32x4 sb = {acc[4], acc[5], acc[6], acc[7]};
        __builtin_nontemporal_store(sb, &t14[(size_t)n * 8 + 2 * qf + 1]);
    }
}

// ---------------- fused epilogue ----------------
// Bases: f2 = h + d*s0 + d*t1; g1 = h + d*s0 - d*t1; g2 = h - 3d*s0 + d*t1
__global__ __launch_bounds__(256) void final_kernel(const float* __restrict__ h,
                                                    const float* __restrict__ s0,
                                                    const float* __restrict__ t1,
                                                    const float* __restrict__ dinv,
                                                    const float* __restrict__ W2,
                                                    const float* __restrict__ b2,
                                                    const float* __restrict__ Wc,
                                                    const float* __restrict__ bc,
                                                    const float* __restrict__ wbern,
                                                    float* __restrict__ out, int N) {
    int n = blockIdx.x * 256 + threadIdx.x;
    if (n >= N) return;
    float di = dinv[n];

    float hv[HD], sv[HD], tv[HD];
    {
        const f32x4* a = (const f32x4*)h;
        const f32x4* c = (const f32x4*)s0;
        const f32x4* e = (const f32x4*)t1;
#pragma unroll
        for (int q = 0; q < 8; ++q) {
            f32x4 v;
            v = __builtin_nontemporal_load(&a[(size_t)n * 8 + q]);
            hv[4*q]=v.x; hv[4*q+1]=v.y; hv[4*q+2]=v.z; hv[4*q+3]=v.w;
            v = __builtin_nontemporal_load(&c[(size_t)n * 8 + q]);
            sv[4*q]=v.x; sv[4*q+1]=v.y; sv[4*q+2]=v.z; sv[4*q+3]=v.w;
            v = __builtin_nontemporal_load(&e[(size_t)n * 8 + q]);
            tv[4*q]=v.x; tv[4*q+1]=v.y; tv[4*q+2]=v.z; tv[4*q+3]=v.w;
        }
    }

    // xp = tanh(h@W2 + b2)
    float xp[HD];
#pragma unroll
    for (int j = 0; j < HD; ++j) xp[j] = b2[j];
#pragma unroll
    for (int k = 0; k < HD; ++k) {
        float a = hv[k];
        const float* w = &W2[k * HD];
#pragma unroll
        for (int j = 0; j < HD; ++j) xp[j] = fmaf(a, w[j], xp[j]);
    }
#pragma unroll
    for (int j = 0; j < HD; ++j) xp[j] = fast_tanh(xp[j]);

    float uf[HD], ug[HD], uh[HD];
#pragma unroll
    for (int j = 0; j < HD; ++j) { uf[j] = 0.f; ug[j] = 0.f; uh[j] = 0.f; }
    float vf0 = 0.f, vf1 = 0.f, vg0 = 0.f, vg1 = 0.f, vh0 = 0.f, vh1 = 0.f;
#pragma unroll
    for (int k = 0; k < HD; ++k) {
        float da = di * sv[k];
        float db = di * tv[k];
        float f2k = hv[k] + da + db;
        float g1k = hv[k] + da - db;
        float g2k = hv[k] - 3.0f * da + db;
        const float* w = &W2[k * HD];
#pragma unroll
        for (int j = 0; j < HD; ++j) {
            uf[j] = fmaf(f2k, w[j], uf[j]);
            ug[j] = fmaf(g1k, w[j], ug[j]);
            uh[j] = fmaf(g2k, w[j], uh[j]);
        }
        vf0 = fmaf(f2k, Wc[k * NC + 0], vf0);
        vf1 = fmaf(f2k, Wc[k * NC + 1], vf1);
        vg0 = fmaf(g1k, Wc[k * NC + 0], vg0);
        vg1 = fmaf(g1k, Wc[k * NC + 1], vg1);
        vh0 = fmaf(g2k, Wc[k * NC + 0], vh0);
        vh1 = fmaf(g2k, Wc[k * NC + 1], vh1);
    }

    float logits[NL];
#pragma unroll
    for (int i = 0; i < NL; ++i) {
        float wa = 0.25f * fmaxf(wbern[i * 3 + 0], 0.0f);
        float wb = 0.50f * fmaxf(wbern[i * 3 + 1], 0.0f);
        float wc = 0.25f * fmaxf(wbern[i * 3 + 2], 0.0f);
        float lg = 0.0f;
#pragma unroll
        for (int j = 0; j < HD; ++j) {
            float p = fmaf(wa, uf[j], fmaf(wb, ug[j], fmaf(wc, uh[j], b2[j])));
            lg = fmaf(fast_tanh(p), xp[j], lg);
        }
        logits[i] = lg;
    }

    float m = fmaxf(logits[0], fmaxf(logits[1], logits[2]));
    float e0 = __expf(logits[0] - m), e1 = __expf(logits[1] - m), e2 = __expf(logits[2] - m);
    float inv = 1.0f / (e0 + e1 + e2);
    float scs[NL] = {e0 * inv, e1 * inv, e2 * inv};

    float A = 0.0f, B = 0.0f, Cc = 0.0f;
#pragma unroll
    for (int i = 0; i < NL; ++i) {
        A  += scs[i] * 0.25f * fmaxf(wbern[i * 3 + 0], 0.0f);
        B  += scs[i] * 0.50f * fmaxf(wbern[i * 3 + 1], 0.0f);
        Cc += scs[i] * 0.25f * fmaxf(wbern[i * 3 + 2], 0.0f);
    }
    out[(size_t)n * NC + 0] = bc[0] + A * vf0 + B * vg0 + Cc * vh0;
    out[(size_t)n * NC + 1] = bc[1] + A * vf1 + B * vg1 + Cc * vh1;
}

extern "C" void kernel_launch(void* const* d_in, const int* in_sizes, int n_in,
                              void* d_out, int out_size, void* d_ws, size_t ws_size,
                              hipStream_t stream) {
    const float* feature = (const float*)d_in[0];
    const float* W1 = (const float*)d_in[1];
    const float* b1 = (const float*)d_in[2];
    const float* W2 = (const float*)d_in[3];
    const float* b2 = (const float*)d_in[4];
    const float* Wc = (const float*)d_in[5];
    const float* bc = (const float*)d_in[6];
    const float* wbern = (const float*)d_in[7];
    const int* src = (const int*)d_in[8];
    const int* dst = (const int*)d_in[9];

    const int N = in_sizes[0] / FIN;   // 100000
    const int E = in_sizes[8];         // 1600000
    const int B = (N + 127) >> 7;      // 782 buckets

    // workspace layout
    char* p = (char*)d_ws;
    size_t Np = ((size_t)N + 255) & ~(size_t)255;
    size_t N32 = (size_t)N * HD;
    int* gcursor   = (int*)p;              p += ((size_t)BMAX) * 4;
    int* row_start = (int*)p;              p += Np * 4;
    int* degA      = (int*)p;              p += Np * 4;
    float* dinv    = (float*)p;            p += Np * 4;
    unsigned int* bucket_buf = (unsigned int*)p;  p += (size_t)B * CAP * 4;  // becomes col[]
    float* h   = (float*)p;                p += N32 * 4;
    float* s0  = (float*)p;                p += N32 * 4;
    float* t1  = (float*)p;                p += N32 * 4;
    u32x4* hs  = (u32x4*)p;                p += N32 * 2;   // bf16 table, 64B/row
    u32x4* f1s = (u32x4*)p;                p += N32 * 2;

    int bN = (N + 255) / 256;
    int bG = ((N * 8) + 255) / 256;
    int nTiles = (E + TILE - 1) / TILE;

    init_kernel<<<(B + 255) / 256, 256, 0, stream>>>(gcursor, B);
    partition_kernel<<<nTiles, 256, 0, stream>>>(src, dst, gcursor, bucket_buf, E);
    bucket_csr_kernel<<<B, 256, 0, stream>>>(bucket_buf, gcursor, row_start, degA, dinv, N);

    mlp_kernel<<<bN, 256, 0, stream>>>(feature, W1, b1, W2, b2, dinv, h, hs, N);

    const int* col = (const int*)bucket_buf;
    gather1_kernel<<<bG, 256, 0, stream>>>(h, hs, dinv, row_start, degA, col, s0, f1s, N);
    gather2_kernel<<<bG, 256, 0, stream>>>(f1s, row_start, degA, col, t1, N);

    final_kernel<<<bN, 256, 0, stream>>>(h, s0, t1, dinv, W2, b2, Wc, bc,
                                         wbern, (float*)d_out, N);
}

// Round 9
// 252.263 us; speedup vs baseline: 1.2095x; 1.0007x over previous
//
#include <hip/hip_runtime.h>
#include <math.h>

#define HD 32      // hidden dim
#define FIN 64     // input features
#define NL 3       // num BernConv layers
#define NC 2       // num classes

#define TILE 8192  // edges per partition tile
#define CAP  3072  // max edges per bucket (mean ~2046, 12 sigma margin)
#define BMAX 1024  // max buckets (N <= 131072 with 128 nodes/bucket)

// clang native vectors (required by __builtin_nontemporal_*)
typedef float  f32x4 __attribute__((ext_vector_type(4)));
typedef unsigned int u32x4 __attribute__((ext_vector_type(4)));

// fast tanh; |rel err| ~1e-7, threshold 7e-2
__device__ __forceinline__ float fast_tanh(float x) {
    float e = __expf(2.0f * x);
    return 1.0f - 2.0f * __builtin_amdgcn_rcpf(e + 1.0f);
}

// fp32 -> bf16 bits, RNE
__device__ __forceinline__ unsigned int f2bf(float f) {
    unsigned int u = __float_as_uint(f);
    return (u + 0x7fffu + ((u >> 16) & 1u)) >> 16;
}
__device__ __forceinline__ unsigned int pack2(float lo, float hi) {
    return f2bf(lo) | (f2bf(hi) << 16);
}
__device__ __forceinline__ float bflo(unsigned int u) { return __uint_as_float(u << 16); }
__device__ __forceinline__ float bfhi(unsigned int u) { return __uint_as_float(u & 0xffff0000u); }

// ---------------- gcursor init ----------------
__global__ __launch_bounds__(256) void init_kernel(int* __restrict__ gcursor, int B) {
    int b = blockIdx.x * 256 + threadIdx.x;
    if (b < B) gcursor[b] = b * CAP;
}

// ---------------- LDS-staged partition: bucket edges by dst>>7 ----------------
__global__ __launch_bounds__(256) void partition_kernel(const int* __restrict__ src,
                                                        const int* __restrict__ dst,
                                                        int* __restrict__ gcursor,
                                                        unsigned int* __restrict__ bucket_buf,
                                                        int E) {
    __shared__ unsigned int vals[TILE];
    __shared__ unsigned short bid[TILE];
    __shared__ int hist[BMAX];
    __shared__ int lcur[BMAX];
    __shared__ int goff[BMAX];
    __shared__ int sc[256];
    int t = threadIdx.x;
    int tile_base = blockIdx.x * TILE;
    int n_tile = min(TILE, E - tile_base);

    for (int i = t; i < BMAX; i += 256) hist[i] = 0;
    __syncthreads();

    unsigned int pk[TILE / 256];
    int bk[TILE / 256];
#pragma unroll
    for (int k = 0; k < TILE / 256; ++k) {
        int e = tile_base + k * 256 + t;
        if (e < E) {
            int s = src[e], d = dst[e];
            int b = d >> 7;
            pk[k] = ((unsigned)s << 7) | (unsigned)(d & 127);
            bk[k] = b;
            atomicAdd(&hist[b], 1);
        } else bk[k] = -1;
    }
    __syncthreads();

    int base4 = t * 4;
    int sum4 = hist[base4] + hist[base4 + 1] + hist[base4 + 2] + hist[base4 + 3];
    sc[t] = sum4;
    __syncthreads();
    for (int off = 1; off < 256; off <<= 1) {
        int v = (t >= off) ? sc[t - off] : 0;
        __syncthreads();
        sc[t] += v;
        __syncthreads();
    }
    int run = sc[t] - sum4;
#pragma unroll
    for (int j = 0; j < 4; ++j) {
        int tmp = hist[base4 + j];
        hist[base4 + j] = run;
        lcur[base4 + j] = run;
        run += tmp;
    }
    __syncthreads();

#pragma unroll
    for (int k = 0; k < TILE / 256; ++k) {
        if (bk[k] >= 0) {
            int pos = atomicAdd(&lcur[bk[k]], 1);
            vals[pos] = pk[k];
            bid[pos] = (unsigned short)bk[k];
        }
    }
    __syncthreads();

    for (int b = t; b < BMAX; b += 256) {
        int cnt = lcur[b] - hist[b];
        goff[b] = (cnt > 0) ? atomicAdd(&gcursor[b], cnt) : 0;
    }
    __syncthreads();

    for (int i = t; i < n_tile; i += 256) {
        int b = bid[i];
        int addr = goff[b] + (i - hist[b]);
        if (addr < (b + 1) * CAP)
            bucket_buf[addr] = vals[i];
    }
}

// ---------------- per-bucket CSR build (in place) ----------------
__global__ __launch_bounds__(256) void bucket_csr_kernel(unsigned int* bucket_buf,
                                                         const int* __restrict__ gcursor,
                                                         int* __restrict__ row_start,
                                                         int* __restrict__ degA,
                                                         float* __restrict__ dinv,
                                                         int N) {
    __shared__ int ldeg[128], lexc[128], lcur2[128];
    __shared__ int colLDS[CAP];
    int b = blockIdx.x;
    int t = threadIdx.x;
    int base = b * CAP;
    int cnt = min(gcursor[b] - base, CAP);

    if (t < 128) ldeg[t] = 0;
    __syncthreads();
    for (int i = t; i < cnt; i += 256)
        atomicAdd(&ldeg[bucket_buf[base + i] & 127], 1);
    __syncthreads();

    if (t < 128) lexc[t] = ldeg[t];
    __syncthreads();
    for (int off = 1; off < 128; off <<= 1) {
        int v = (t >= off && t < 128) ? lexc[t - off] : 0;
        __syncthreads();
        if (t < 128) lexc[t] += v;
        __syncthreads();
    }
    if (t < 128) {
        int ex = lexc[t] - ldeg[t];
        lcur2[t] = ex;
        int node = (b << 7) + t;
        if (node < N) {
            row_start[node] = base + ex;
            degA[node] = ldeg[t];
            dinv[node] = rsqrtf(fmaxf((float)ldeg[t], 1.0f));
        }
    }
    __syncthreads();

    for (int i = t; i < cnt; i += 256) {
        unsigned int v = bucket_buf[base + i];
        int pos = atomicAdd(&lcur2[(int)(v & 127)], 1);
        colLDS[pos] = (int)(v >> 7);
    }
    __syncthreads();
    for (int i = t; i < cnt; i += 256)
        bucket_buf[base + i] = (unsigned int)colLDS[i];   // now = col[]
}

// ---------------- MLP in: h = relu(feat@W1+b1)@W2+b2 ----------------
// Feature tile staged via LDS: coalesced 16B global loads -> stride-65 padded
// rows -> conflict-free b32 reads ((t+k) mod 32). Weights stay wave-uniform
// (SGPR loads). Plain stores (NT caused 2.4x write amplification, r8).
__global__ __launch_bounds__(256) void mlp_kernel(const float* __restrict__ feat,
                                                  const float* __restrict__ W1,
                                                  const float* __restrict__ b1,
                                                  const float* __restrict__ W2,
                                                  const float* __restrict__ b2,
                                                  const float* __restrict__ dinv,
                                                  float* __restrict__ hout,
                                                  u32x4* __restrict__ hs, int N) {
    __shared__ float sf[256 * (FIN + 1)];
    int t = threadIdx.x;
    int base = blockIdx.x * 256;
    int nrows = min(256, N - base);
    int nElem = nrows * FIN;
    const f32x4* fp = (const f32x4*)(feat + (size_t)base * FIN);
    for (int i = t * 4; i < nElem; i += 256 * 4) {
        f32x4 v = fp[i >> 2];
        int row = i >> 6, colx = i & 63;
        float* d = &sf[row * (FIN + 1) + colx];
        d[0] = v.x; d[1] = v.y; d[2] = v.z; d[3] = v.w;
    }
    __syncthreads();
    int n = base + t;
    if (n >= N) return;

    const float* myrow = &sf[t * (FIN + 1)];
    float h1[HD];
#pragma unroll
    for (int j = 0; j < HD; ++j) h1[j] = b1[j];
#pragma unroll
    for (int k = 0; k < FIN; ++k) {
        float a = myrow[k];
        const float* w = &W1[k * HD];
#pragma unroll
        for (int j = 0; j < HD; ++j) h1[j] = fmaf(a, w[j], h1[j]);
    }
    float h2[HD];
#pragma unroll
    for (int j = 0; j < HD; ++j) h2[j] = b2[j];
#pragma unroll
    for (int k = 0; k < HD; ++k) {
        float a = fmaxf(h1[k], 0.0f);
#pragma unroll
        for (int j = 0; j < HD; ++j) h2[j] = fmaf(a, W2[k * HD + j], h2[j]);
    }

    f32x4* op = (f32x4*)hout;
#pragma unroll
    for (int q = 0; q < HD / 4; ++q) {
        f32x4 v = {h2[4 * q], h2[4 * q + 1], h2[4 * q + 2], h2[4 * q + 3]};
        op[(size_t)n * 8 + q] = v;
    }
    float di = dinv[n];
#pragma unroll
    for (int q = 0; q < 4; ++q) {   // quad q covers feats [8q, 8q+8)
        u32x4 u;
        u.x = pack2(di * h2[8 * q + 0], di * h2[8 * q + 1]);
        u.y = pack2(di * h2[8 * q + 2], di * h2[8 * q + 3]);
        u.z = pack2(di * h2[8 * q + 4], di * h2[8 * q + 5]);
        u.w = pack2(di * h2[8 * q + 6], di * h2[8 * q + 7]);
        hs[(size_t)n * 4 + q] = u;
    }
}

// ---------------- gather #1: acc = sum hs[col]; s0 = acc (fp32);
//                  f1s = bf16(d*(h + d*acc)) ----------------
// 8 lanes/node: 4 feature-quads x 2 edge-parity walks; shfl_xor(4) combine.
__global__ __launch_bounds__(256) void gather1_kernel(const float* __restrict__ h,
                                                      const u32x4* __restrict__ hs,
                                                      const float* __restrict__ dinv,
                                                      const int* __restrict__ row_start,
                                                      const int* __restrict__ deg,
                                                      const int* __restrict__ col,
                                                      float* __restrict__ s0,
                                                      u32x4* __restrict__ f1s, int N) {
    int t = blockIdx.x * 256 + threadIdx.x;
    int n = t >> 3;
    if (n >= N) return;
    int sub = t & 7;
    int qf = sub & 3;       // feature quad
    int eh = sub >> 2;      // edge parity
    int s = row_start[n];
    int e_end = s + deg[n];
    float acc[8] = {0.f, 0.f, 0.f, 0.f, 0.f, 0.f, 0.f, 0.f};
    for (int e = s + eh; e < e_end; e += 2) {
        int c = __builtin_nontemporal_load(&col[e]);
        u32x4 v = hs[(size_t)c * 4 + qf];
        acc[0] += bflo(v.x); acc[1] += bfhi(v.x);
        acc[2] += bflo(v.y); acc[3] += bfhi(v.y);
        acc[4] += bflo(v.z); acc[5] += bfhi(v.z);
        acc[6] += bflo(v.w); acc[7] += bfhi(v.w);
    }
#pragma unroll
    for (int i = 0; i < 8; ++i) acc[i] += __shfl_xor(acc[i], 4);

    float di = dinv[n];
    f32x4* s04 = (f32x4*)s0;
    if (eh == 0) {
        f32x4 sa = {acc[0], acc[1], acc[2], acc[3]};
        s04[(size_t)n * 8 + 2 * qf] = sa;
    } else {
        f32x4 sb = {acc[4], acc[5], acc[6], acc[7]};
        s04[(size_t)n * 8 + 2 * qf + 1] = sb;
        const f32x4* h4 = (const f32x4*)h;
        f32x4 ha = h4[(size_t)n * 8 + 2 * qf];
        f32x4 hb = h4[(size_t)n * 8 + 2 * qf + 1];
        u32x4 u;
        u.x = pack2(di * fmaf(di, acc[0], ha.x), di * fmaf(di, acc[1], ha.y));
        u.y = pack2(di * fmaf(di, acc[2], ha.z), di * fmaf(di, acc[3], ha.w));
        u.z = pack2(di * fmaf(di, acc[4], hb.x), di * fmaf(di, acc[5], hb.y));
        u.w = pack2(di * fmaf(di, acc[6], hb.z), di * fmaf(di, acc[7], hb.w));
        f1s[(size_t)n * 4 + qf] = u;    // next kernel's gather table
    }
}

// ---------------- gather #2: t1 = sum f1s[col] ----------------
__global__ __launch_bounds__(256) void gather2_kernel(const u32x4* __restrict__ f1s,
                                                      const int* __restrict__ row_start,
                                                      const int* __restrict__ deg,
                                                      const int* __restrict__ col,
                                                      float* __restrict__ t1, int N) {
    int t = blockIdx.x * 256 + threadIdx.x;
    int n = t >> 3;
    if (n >= N) return;
    int sub = t & 7;
    int qf = sub & 3;
    int eh = sub >> 2;
    int s = row_start[n];
    int e_end = s + deg[n];
    float acc[8] = {0.f, 0.f, 0.f, 0.f, 0.f, 0.f, 0.f, 0.f};
    for (int e = s + eh; e < e_end; e += 2) {
        int c = __builtin_nontemporal_load(&col[e]);
        u32x4 v = f1s[(size_t)c * 4 + qf];
        acc[0] += bflo(v.x); acc[1] += bfhi(v.x);
        acc[2] += bflo(v.y); acc[3] += bfhi(v.y);
        acc[4] += bflo(v.z); acc[5] += bfhi(v.z);
        acc[6] += bflo(v.w); acc[7] += bfhi(v.w);
    }
#pragma unroll
    for (int i = 0; i < 8; ++i) acc[i] += __shfl_xor(acc[i], 4);

    f32x4* t14 = (f32x4*)t1;
    if (eh == 0) {
        f32x4 sa = {acc[0], acc[1], acc[2], acc[3]};
        t14[(size_t)n * 8 + 2 * qf] = sa;
    } else {
        f32x4 sb = {acc[4], acc[5], acc[6], acc[7]};
        t14[(size_t)n * 8 + 2 * qf + 1] = sb;
    }
}

// ---------------- fused epilogue ----------------
// Bases: f2 = h + d*s0 + d*t1; g1 = h + d*s0 - d*t1; g2 = h - 3d*s0 + d*t1
__global__ __launch_bounds__(256) void final_kernel(const float* __restrict__ h,
                                                    const float* __restrict__ s0,
                                                    const float* __restrict__ t1,
                                                    const float* __restrict__ dinv,
                                                    const float* __restrict__ W2,
                                                    const float* __restrict__ b2,
                                                    const float* __restrict__ Wc,
                                                    const float* __restrict__ bc,
                                                    const float* __restrict__ wbern,
                                                    float* __restrict__ out, int N) {
    int n = blockIdx.x * 256 + threadIdx.x;
    if (n >= N) return;
    float di = dinv[n];

    float hv[HD], sv[HD], tv[HD];
    {
        const f32x4* a = (const f32x4*)h;
        const f32x4* c = (const f32x4*)s0;
        const f32x4* e = (const f32x4*)t1;
#pragma unroll
        for (int q = 0; q < 8; ++q) {
            f32x4 v;
            v = a[(size_t)n * 8 + q];
            hv[4*q]=v.x; hv[4*q+1]=v.y; hv[4*q+2]=v.z; hv[4*q+3]=v.w;
            v = c[(size_t)n * 8 + q];
            sv[4*q]=v.x; sv[4*q+1]=v.y; sv[4*q+2]=v.z; sv[4*q+3]=v.w;
            v = e[(size_t)n * 8 + q];
            tv[4*q]=v.x; tv[4*q+1]=v.y; tv[4*q+2]=v.z; tv[4*q+3]=v.w;
        }
    }

    // xp = tanh(h@W2 + b2)
    float xp[HD];
#pragma unroll
    for (int j = 0; j < HD; ++j) xp[j] = b2[j];
#pragma unroll
    for (int k = 0; k < HD; ++k) {
        float a = hv[k];
        const float* w = &W2[k * HD];
#pragma unroll
        for (int j = 0; j < HD; ++j) xp[j] = fmaf(a, w[j], xp[j]);
    }
#pragma unroll
    for (int j = 0; j < HD; ++j) xp[j] = fast_tanh(xp[j]);

    float uf[HD], ug[HD], uh[HD];
#pragma unroll
    for (int j = 0; j < HD; ++j) { uf[j] = 0.f; ug[j] = 0.f; uh[j] = 0.f; }
    float vf0 = 0.f, vf1 = 0.f, vg0 = 0.f, vg1 = 0.f, vh0 = 0.f, vh1 = 0.f;
#pragma unroll
    for (int k = 0; k < HD; ++k) {
        float da = di * sv[k];
        float db = di * tv[k];
        float f2k = hv[k] + da + db;
        float g1k = hv[k] + da - db;
        float g2k = hv[k] - 3.0f * da + db;
        const float* w = &W2[k * HD];
#pragma unroll
        for (int j = 0; j < HD; ++j) {
            uf[j] = fmaf(f2k, w[j], uf[j]);
            ug[j] = fmaf(g1k, w[j], ug[j]);
            uh[j] = fmaf(g2k, w[j], uh[j]);
        }
        vf0 = fmaf(f2k, Wc[k * NC + 0], vf0);
        vf1 = fmaf(f2k, Wc[k * NC + 1], vf1);
        vg0 = fmaf(g1k, Wc[k * NC + 0], vg0);
        vg1 = fmaf(g1k, Wc[k * NC + 1], vg1);
        vh0 = fmaf(g2k, Wc[k * NC + 0], vh0);
        vh1 = fmaf(g2k, Wc[k * NC + 1], vh1);
    }

    float logits[NL];
#pragma unroll
    for (int i = 0; i < NL; ++i) {
        float wa = 0.25f * fmaxf(wbern[i * 3 + 0], 0.0f);
        float wb = 0.50f * fmaxf(wbern[i * 3 + 1], 0.0f);
        float wc = 0.25f * fmaxf(wbern[i * 3 + 2], 0.0f);
        float lg = 0.0f;
#pragma unroll
        for (int j = 0; j < HD; ++j) {
            float p = fmaf(wa, uf[j], fmaf(wb, ug[j], fmaf(wc, uh[j], b2[j])));
            lg = fmaf(fast_tanh(p), xp[j], lg);
        }
        logits[i] = lg;
    }

    float m = fmaxf(logits[0], fmaxf(logits[1], logits[2]));
    float e0 = __expf(logits[0] - m), e1 = __expf(logits[1] - m), e2 = __expf(logits[2] - m);
    float inv = 1.0f / (e0 + e1 + e2);
    float scs[NL] = {e0 * inv, e1 * inv, e2 * inv};

    float A = 0.0f, B = 0.0f, Cc = 0.0f;
#pragma unroll
    for (int i = 0; i < NL; ++i) {
        A  += scs[i] * 0.25f * fmaxf(wbern[i * 3 + 0], 0.0f);
        B  += scs[i] * 0.50f * fmaxf(wbern[i * 3 + 1], 0.0f);
        Cc += scs[i] * 0.25f * fmaxf(wbern[i * 3 + 2], 0.0f);
    }
    out[(size_t)n * NC + 0] = bc[0] + A * vf0 + B * vg0 + Cc * vh0;
    out[(size_t)n * NC + 1] = bc[1] + A * vf1 + B * vg1 + Cc * vh1;
}

extern "C" void kernel_launch(void* const* d_in, const int* in_sizes, int n_in,
                              void* d_out, int out_size, void* d_ws, size_t ws_size,
                              hipStream_t stream) {
    const float* feature = (const float*)d_in[0];
    const float* W1 = (const float*)d_in[1];
    const float* b1 = (const float*)d_in[2];
    const float* W2 = (const float*)d_in[3];
    const float* b2 = (const float*)d_in[4];
    const float* Wc = (const float*)d_in[5];
    const float* bc = (const float*)d_in[6];
    const float* wbern = (const float*)d_in[7];
    const int* src = (const int*)d_in[8];
    const int* dst = (const int*)d_in[9];

    const int N = in_sizes[0] / FIN;   // 100000
    const int E = in_sizes[8];         // 1600000
    const int B = (N + 127) >> 7;      // 782 buckets

    // workspace layout
    char* p = (char*)d_ws;
    size_t Np = ((size_t)N + 255) & ~(size_t)255;
    size_t N32 = (size_t)N * HD;
    int* gcursor   = (int*)p;              p += ((size_t)BMAX) * 4;
    int* row_start = (int*)p;              p += Np * 4;
    int* degA      = (int*)p;              p += Np * 4;
    float* dinv    = (float*)p;            p += Np * 4;
    unsigned int* bucket_buf = (unsigned int*)p;  p += (size_t)B * CAP * 4;  // becomes col[]
    float* h   = (float*)p;                p += N32 * 4;
    float* s0  = (float*)p;                p += N32 * 4;
    float* t1  = (float*)p;                p += N32 * 4;
    u32x4* hs  = (u32x4*)p;                p += N32 * 2;   // bf16 table, 64B/row
    u32x4* f1s = (u32x4*)p;                p += N32 * 2;

    int bN = (N + 255) / 256;
    int bG = ((N * 8) + 255) / 256;
    int nTiles = (E + TILE - 1) / TILE;

    init_kernel<<<(B + 255) / 256, 256, 0, stream>>>(gcursor, B);
    partition_kernel<<<nTiles, 256, 0, stream>>>(src, dst, gcursor, bucket_buf, E);
    bucket_csr_kernel<<<B, 256, 0, stream>>>(bucket_buf, gcursor, row_start, degA, dinv, N);

    mlp_kernel<<<bN, 256, 0, stream>>>(feature, W1, b1, W2, b2, dinv, h, hs, N);

    const int* col = (const int*)bucket_buf;
    gather1_kernel<<<bG, 256, 0, stream>>>(h, hs, dinv, row_start, degA, col, s0, f1s, N);
    gather2_kernel<<<bG, 256, 0, stream>>>(f1s, row_start, degA, col, t1, N);

    final_kernel<<<bN, 256, 0, stream>>>(h, s0, t1, dinv, W2, b2, Wc, bc,
                                         wbern, (float*)d_out, N);
}

// Round 10
// 242.249 us; speedup vs baseline: 1.2595x; 1.0413x over previous
//
#include <hip/hip_runtime.h>
#include <math.h>
#include <stdint.h>

#define HD 32      // hidden dim
#define FIN 64     // input features
#define NL 3       // num BernConv layers
#define NC 2       // num classes

#define TILE 8192  // edges per partition tile
#define CAP  3072  // max edges per bucket (mean ~2046, 12 sigma margin)
#define BMAX 1024  // max buckets (N <= 131072 with 128 nodes/bucket)

// clang native vectors (required by __builtin_nontemporal_*)
typedef float  f32x4 __attribute__((ext_vector_type(4)));
typedef unsigned int u32x4 __attribute__((ext_vector_type(4)));

// fast tanh; |rel err| ~1e-7, threshold 7e-2
__device__ __forceinline__ float fast_tanh(float x) {
    float e = __expf(2.0f * x);
    return 1.0f - 2.0f * __builtin_amdgcn_rcpf(e + 1.0f);
}

// fp32 -> bf16 bits, RNE
__device__ __forceinline__ unsigned int f2bf(float f) {
    unsigned int u = __float_as_uint(f);
    return (u + 0x7fffu + ((u >> 16) & 1u)) >> 16;
}
__device__ __forceinline__ unsigned int pack2(float lo, float hi) {
    return f2bf(lo) | (f2bf(hi) << 16);
}
__device__ __forceinline__ float bflo(unsigned int u) { return __uint_as_float(u << 16); }
__device__ __forceinline__ float bfhi(unsigned int u) { return __uint_as_float(u & 0xffff0000u); }

// async global->LDS DMA, 16B per lane (CK-style addrspace cast via uintptr)
__device__ __forceinline__ void load_lds16(const void* g, void* l) {
    auto* gp = (const __attribute__((address_space(1))) unsigned int*)(uintptr_t)g;
    auto* lp = (__attribute__((address_space(3))) unsigned int*)(unsigned int)(uintptr_t)l;
    __builtin_amdgcn_global_load_lds(gp, lp, 16, 0, 0);
}

// ---------------- gcursor init ----------------
__global__ __launch_bounds__(256) void init_kernel(int* __restrict__ gcursor, int B) {
    int b = blockIdx.x * 256 + threadIdx.x;
    if (b < B) gcursor[b] = b * CAP;
}

// ---------------- LDS-staged partition: bucket edges by dst>>7 ----------------
__global__ __launch_bounds__(256) void partition_kernel(const int* __restrict__ src,
                                                        const int* __restrict__ dst,
                                                        int* __restrict__ gcursor,
                                                        unsigned int* __restrict__ bucket_buf,
                                                        int E) {
    __shared__ unsigned int vals[TILE];
    __shared__ unsigned short bid[TILE];
    __shared__ int hist[BMAX];
    __shared__ int lcur[BMAX];
    __shared__ int goff[BMAX];
    __shared__ int sc[256];
    int t = threadIdx.x;
    int tile_base = blockIdx.x * TILE;
    int n_tile = min(TILE, E - tile_base);

    for (int i = t; i < BMAX; i += 256) hist[i] = 0;
    __syncthreads();

    unsigned int pk[TILE / 256];
    int bk[TILE / 256];
#pragma unroll
    for (int k = 0; k < TILE / 256; ++k) {
        int e = tile_base + k * 256 + t;
        if (e < E) {
            int s = src[e], d = dst[e];
            int b = d >> 7;
            pk[k] = ((unsigned)s << 7) | (unsigned)(d & 127);
            bk[k] = b;
            atomicAdd(&hist[b], 1);
        } else bk[k] = -1;
    }
    __syncthreads();

    int base4 = t * 4;
    int sum4 = hist[base4] + hist[base4 + 1] + hist[base4 + 2] + hist[base4 + 3];
    sc[t] = sum4;
    __syncthreads();
    for (int off = 1; off < 256; off <<= 1) {
        int v = (t >= off) ? sc[t - off] : 0;
        __syncthreads();
        sc[t] += v;
        __syncthreads();
    }
    int run = sc[t] - sum4;
#pragma unroll
    for (int j = 0; j < 4; ++j) {
        int tmp = hist[base4 + j];
        hist[base4 + j] = run;
        lcur[base4 + j] = run;
        run += tmp;
    }
    __syncthreads();

#pragma unroll
    for (int k = 0; k < TILE / 256; ++k) {
        if (bk[k] >= 0) {
            int pos = atomicAdd(&lcur[bk[k]], 1);
            vals[pos] = pk[k];
            bid[pos] = (unsigned short)bk[k];
        }
    }
    __syncthreads();

    for (int b = t; b < BMAX; b += 256) {
        int cnt = lcur[b] - hist[b];
        goff[b] = (cnt > 0) ? atomicAdd(&gcursor[b], cnt) : 0;
    }
    __syncthreads();

    for (int i = t; i < n_tile; i += 256) {
        int b = bid[i];
        int addr = goff[b] + (i - hist[b]);
        if (addr < (b + 1) * CAP)
            bucket_buf[addr] = vals[i];
    }
}

// ---------------- per-bucket CSR build (in place) ----------------
__global__ __launch_bounds__(256) void bucket_csr_kernel(unsigned int* bucket_buf,
                                                         const int* __restrict__ gcursor,
                                                         int* __restrict__ row_start,
                                                         int* __restrict__ degA,
                                                         float* __restrict__ dinv,
                                                         int N) {
    __shared__ int ldeg[128], lexc[128], lcur2[128];
    __shared__ int colLDS[CAP];
    int b = blockIdx.x;
    int t = threadIdx.x;
    int base = b * CAP;
    int cnt = min(gcursor[b] - base, CAP);

    if (t < 128) ldeg[t] = 0;
    __syncthreads();
    for (int i = t; i < cnt; i += 256)
        atomicAdd(&ldeg[bucket_buf[base + i] & 127], 1);
    __syncthreads();

    if (t < 128) lexc[t] = ldeg[t];
    __syncthreads();
    for (int off = 1; off < 128; off <<= 1) {
        int v = (t >= off && t < 128) ? lexc[t - off] : 0;
        __syncthreads();
        if (t < 128) lexc[t] += v;
        __syncthreads();
    }
    if (t < 128) {
        int ex = lexc[t] - ldeg[t];
        lcur2[t] = ex;
        int node = (b << 7) + t;
        if (node < N) {
            row_start[node] = base + ex;
            degA[node] = ldeg[t];
            dinv[node] = rsqrtf(fmaxf((float)ldeg[t], 1.0f));
        }
    }
    __syncthreads();

    for (int i = t; i < cnt; i += 256) {
        unsigned int v = bucket_buf[base + i];
        int pos = atomicAdd(&lcur2[(int)(v & 127)], 1);
        colLDS[pos] = (int)(v >> 7);
    }
    __syncthreads();
    for (int i = t; i < cnt; i += 256)
        bucket_buf[base + i] = (unsigned int)colLDS[i];   // now = col[]
}

// ---------------- MLP in: h = relu(feat@W1+b1)@W2+b2 ----------------
// Feature tile staged via global_load_lds width-16 DMA: each wave issues its
// 16 chunk copies with NO intervening waitcnt (the r9 reg-staging loop
// serialized on vmcnt(0) per iteration — that was the 45us). One drain at the
// barrier. Natural row-major LDS layout (DMA can't pad); the 16-way bank
// conflict on ds_read_b128 (~1.1K cyc/wave) hides under 6.1K cyc of FMA issue.
__global__ __launch_bounds__(256) void mlp_kernel(const float* __restrict__ feat,
                                                  const float* __restrict__ W1,
                                                  const float* __restrict__ b1,
                                                  const float* __restrict__ W2,
                                                  const float* __restrict__ b2,
                                                  const float* __restrict__ dinv,
                                                  float* __restrict__ hout,
                                                  u32x4* __restrict__ hs, int N) {
    __shared__ float sf[256 * FIN];    // 64 KB
    int t = threadIdx.x;
    int lane = t & 63;
    int wv = t >> 6;
    int base = blockIdx.x * 256;
    int nrows = min(256, N - base);

    // DMA full 4-row chunks (1 KB each): chunk c covers rows [4c, 4c+4)
    const char* gbase = (const char*)(feat + (size_t)base * FIN);
#pragma unroll
    for (int it = 0; it < 16; ++it) {
        int c = wv * 16 + it;
        if (c * 4 + 3 < nrows)
            load_lds16(gbase + (size_t)c * 1024 + (size_t)lane * 16,
                       (char*)sf + (size_t)c * 1024);
    }
    // tail rows (nrows % 4): plain guarded copy
    int done = (nrows >> 2) << 2;
    for (int r = done + wv; r < nrows; r += 4)
        sf[r * FIN + lane] = feat[((size_t)base + r) * FIN + lane];
    __syncthreads();

    int n = base + t;
    if (n >= N) return;

    const f32x4* myrow = (const f32x4*)&sf[t * FIN];
    float h1[HD];
#pragma unroll
    for (int j = 0; j < HD; ++j) h1[j] = b1[j];
#pragma unroll
    for (int k4 = 0; k4 < FIN / 4; ++k4) {
        f32x4 v = myrow[k4];
        const float* w = &W1[k4 * 4 * HD];
#pragma unroll
        for (int j = 0; j < HD; ++j)
            h1[j] = fmaf(v.w, w[3 * HD + j],
                    fmaf(v.z, w[2 * HD + j],
                    fmaf(v.y, w[1 * HD + j],
                    fmaf(v.x, w[0 * HD + j], h1[j]))));
    }
    float h2[HD];
#pragma unroll
    for (int j = 0; j < HD; ++j) h2[j] = b2[j];
#pragma unroll
    for (int k = 0; k < HD; ++k) {
        float a = fmaxf(h1[k], 0.0f);
#pragma unroll
        for (int j = 0; j < HD; ++j) h2[j] = fmaf(a, W2[k * HD + j], h2[j]);
    }

    f32x4* op = (f32x4*)hout;
#pragma unroll
    for (int q = 0; q < HD / 4; ++q) {
        f32x4 v = {h2[4 * q], h2[4 * q + 1], h2[4 * q + 2], h2[4 * q + 3]};
        op[(size_t)n * 8 + q] = v;
    }
    float di = dinv[n];
#pragma unroll
    for (int q = 0; q < 4; ++q) {   // quad q covers feats [8q, 8q+8)
        u32x4 u;
        u.x = pack2(di * h2[8 * q + 0], di * h2[8 * q + 1]);
        u.y = pack2(di * h2[8 * q + 2], di * h2[8 * q + 3]);
        u.z = pack2(di * h2[8 * q + 4], di * h2[8 * q + 5]);
        u.w = pack2(di * h2[8 * q + 6], di * h2[8 * q + 7]);
        hs[(size_t)n * 4 + q] = u;
    }
}

// ---------------- gather #1: acc = sum hs[col]; s0 = acc (fp32);
//                  f1s = bf16(d*(h + d*acc)) ----------------
// 8 lanes/node: 4 feature-quads x 2 edge-parity walks; shfl_xor(4) combine.
__global__ __launch_bounds__(256) void gather1_kernel(const float* __restrict__ h,
                                                      const u32x4* __restrict__ hs,
                                                      const float* __restrict__ dinv,
                                                      const int* __restrict__ row_start,
                                                      const int* __restrict__ deg,
                                                      const int* __restrict__ col,
                                                      float* __restrict__ s0,
                                                      u32x4* __restrict__ f1s, int N) {
    int t = blockIdx.x * 256 + threadIdx.x;
    int n = t >> 3;
    if (n >= N) return;
    int sub = t & 7;
    int qf = sub & 3;       // feature quad
    int eh = sub >> 2;      // edge parity
    int s = row_start[n];
    int e_end = s + deg[n];
    float acc[8] = {0.f, 0.f, 0.f, 0.f, 0.f, 0.f, 0.f, 0.f};
    for (int e = s + eh; e < e_end; e += 2) {
        int c = __builtin_nontemporal_load(&col[e]);
        u32x4 v = hs[(size_t)c * 4 + qf];
        acc[0] += bflo(v.x); acc[1] += bfhi(v.x);
        acc[2] += bflo(v.y); acc[3] += bfhi(v.y);
        acc[4] += bflo(v.z); acc[5] += bfhi(v.z);
        acc[6] += bflo(v.w); acc[7] += bfhi(v.w);
    }
#pragma unroll
    for (int i = 0; i < 8; ++i) acc[i] += __shfl_xor(acc[i], 4);

    float di = dinv[n];
    f32x4* s04 = (f32x4*)s0;
    if (eh == 0) {
        f32x4 sa = {acc[0], acc[1], acc[2], acc[3]};
        s04[(size_t)n * 8 + 2 * qf] = sa;
    } else {
        f32x4 sb = {acc[4], acc[5], acc[6], acc[7]};
        s04[(size_t)n * 8 + 2 * qf + 1] = sb;
        const f32x4* h4 = (const f32x4*)h;
        f32x4 ha = h4[(size_t)n * 8 + 2 * qf];
        f32x4 hb = h4[(size_t)n * 8 + 2 * qf + 1];
        u32x4 u;
        u.x = pack2(di * fmaf(di, acc[0], ha.x), di * fmaf(di, acc[1], ha.y));
        u.y = pack2(di * fmaf(di, acc[2], ha.z), di * fmaf(di, acc[3], ha.w));
        u.z = pack2(di * fmaf(di, acc[4], hb.x), di * fmaf(di, acc[5], hb.y));
        u.w = pack2(di * fmaf(di, acc[6], hb.z), di * fmaf(di, acc[7], hb.w));
        f1s[(size_t)n * 4 + qf] = u;    // next kernel's gather table
    }
}

// ---------------- gather #2: t1 = sum f1s[col] ----------------
__global__ __launch_bounds__(256) void gather2_kernel(const u32x4* __restrict__ f1s,
                                                      const int* __restrict__ row_start,
                                                      const int* __restrict__ deg,
                                                      const int* __restrict__ col,
                                                      float* __restrict__ t1, int N) {
    int t = blockIdx.x * 256 + threadIdx.x;
    int n = t >> 3;
    if (n >= N) return;
    int sub = t & 7;
    int qf = sub & 3;
    int eh = sub >> 2;
    int s = row_start[n];
    int e_end = s + deg[n];
    float acc[8] = {0.f, 0.f, 0.f, 0.f, 0.f, 0.f, 0.f, 0.f};
    for (int e = s + eh; e < e_end; e += 2) {
        int c = __builtin_nontemporal_load(&col[e]);
        u32x4 v = f1s[(size_t)c * 4 + qf];
        acc[0] += bflo(v.x); acc[1] += bfhi(v.x);
        acc[2] += bflo(v.y); acc[3] += bfhi(v.y);
        acc[4] += bflo(v.z); acc[5] += bfhi(v.z);
        acc[6] += bflo(v.w); acc[7] += bfhi(v.w);
    }
#pragma unroll
    for (int i = 0; i < 8; ++i) acc[i] += __shfl_xor(acc[i], 4);

    f32x4* t14 = (f32x4*)t1;
    if (eh == 0) {
        f32x4 sa = {acc[0], acc[1], acc[2], acc[3]};
        t14[(size_t)n * 8 + 2 * qf] = sa;
    } else {
        f32x4 sb = {acc[4], acc[5], acc[6], acc[7]};
        t14[(size_t)n * 8 + 2 * qf + 1] = sb;
    }
}

// ---------------- fused epilogue ----------------
// Bases: f2 = h + d*s0 + d*t1; g1 = h + d*s0 - d*t1; g2 = h - 3d*s0 + d*t1
__global__ __launch_bounds__(256) void final_kernel(const float* __restrict__ h,
                                                    const float* __restrict__ s0,
                                                    const float* __restrict__ t1,
                                                    const float* __restrict__ dinv,
                                                    const float* __restrict__ W2,
                                                    const float* __restrict__ b2,
                                                    const float* __restrict__ Wc,
                                                    const float* __restrict__ bc,
                                                    const float* __restrict__ wbern,
                                                    float* __restrict__ out, int N) {
    int n = blockIdx.x * 256 + threadIdx.x;
    if (n >= N) return;
    float di = dinv[n];

    float hv[HD], sv[HD], tv[HD];
    {
        const f32x4* a = (const f32x4*)h;
        const f32x4* c = (const f32x4*)s0;
        const f32x4* e = (const f32x4*)t1;
#pragma unroll
        for (int q = 0; q < 8; ++q) {
            f32x4 v;
            v = a[(size_t)n * 8 + q];
            hv[4*q]=v.x; hv[4*q+1]=v.y; hv[4*q+2]=v.z; hv[4*q+3]=v.w;
            v = c[(size_t)n * 8 + q];
            sv[4*q]=v.x; sv[4*q+1]=v.y; sv[4*q+2]=v.z; sv[4*q+3]=v.w;
            v = e[(size_t)n * 8 + q];
            tv[4*q]=v.x; tv[4*q+1]=v.y; tv[4*q+2]=v.z; tv[4*q+3]=v.w;
        }
    }

    // xp = tanh(h@W2 + b2)
    float xp[HD];
#pragma unroll
    for (int j = 0; j < HD; ++j) xp[j] = b2[j];
#pragma unroll
    for (int k = 0; k < HD; ++k) {
        float a = hv[k];
        const float* w = &W2[k * HD];
#pragma unroll
        for (int j = 0; j < HD; ++j) xp[j] = fmaf(a, w[j], xp[j]);
    }
#pragma unroll
    for (int j = 0; j < HD; ++j) xp[j] = fast_tanh(xp[j]);

    float uf[HD], ug[HD], uh[HD];
#pragma unroll
    for (int j = 0; j < HD; ++j) { uf[j] = 0.f; ug[j] = 0.f; uh[j] = 0.f; }
    float vf0 = 0.f, vf1 = 0.f, vg0 = 0.f, vg1 = 0.f, vh0 = 0.f, vh1 = 0.f;
#pragma unroll
    for (int k = 0; k < HD; ++k) {
        float da = di * sv[k];
        float db = di * tv[k];
        float f2k = hv[k] + da + db;
        float g1k = hv[k] + da - db;
        float g2k = hv[k] - 3.0f * da + db;
        const float* w = &W2[k * HD];
#pragma unroll
        for (int j = 0; j < HD; ++j) {
            uf[j] = fmaf(f2k, w[j], uf[j]);
            ug[j] = fmaf(g1k, w[j], ug[j]);
            uh[j] = fmaf(g2k, w[j], uh[j]);
        }
        vf0 = fmaf(f2k, Wc[k * NC + 0], vf0);
        vf1 = fmaf(f2k, Wc[k * NC + 1], vf1);
        vg0 = fmaf(g1k, Wc[k * NC + 0], vg0);
        vg1 = fmaf(g1k, Wc[k * NC + 1], vg1);
        vh0 = fmaf(g2k, Wc[k * NC + 0], vh0);
        vh1 = fmaf(g2k, Wc[k * NC + 1], vh1);
    }

    float logits[NL];
#pragma unroll
    for (int i = 0; i < NL; ++i) {
        float wa = 0.25f * fmaxf(wbern[i * 3 + 0], 0.0f);
        float wb = 0.50f * fmaxf(wbern[i * 3 + 1], 0.0f);
        float wc = 0.25f * fmaxf(wbern[i * 3 + 2], 0.0f);
        float lg = 0.0f;
#pragma unroll
        for (int j = 0; j < HD; ++j) {
            float p = fmaf(wa, uf[j], fmaf(wb, ug[j], fmaf(wc, uh[j], b2[j])));
            lg = fmaf(fast_tanh(p), xp[j], lg);
        }
        logits[i] = lg;
    }

    float m = fmaxf(logits[0], fmaxf(logits[1], logits[2]));
    float e0 = __expf(logits[0] - m), e1 = __expf(logits[1] - m), e2 = __expf(logits[2] - m);
    float inv = 1.0f / (e0 + e1 + e2);
    float scs[NL] = {e0 * inv, e1 * inv, e2 * inv};

    float A = 0.0f, B = 0.0f, Cc = 0.0f;
#pragma unroll
    for (int i = 0; i < NL; ++i) {
        A  += scs[i] * 0.25f * fmaxf(wbern[i * 3 + 0], 0.0f);
        B  += scs[i] * 0.50f * fmaxf(wbern[i * 3 + 1], 0.0f);
        Cc += scs[i] * 0.25f * fmaxf(wbern[i * 3 + 2], 0.0f);
    }
    out[(size_t)n * NC + 0] = bc[0] + A * vf0 + B * vg0 + Cc * vh0;
    out[(size_t)n * NC + 1] = bc[1] + A * vf1 + B * vg1 + Cc * vh1;
}

extern "C" void kernel_launch(void* const* d_in, const int* in_sizes, int n_in,
                              void* d_out, int out_size, void* d_ws, size_t ws_size,
                              hipStream_t stream) {
    const float* feature = (const float*)d_in[0];
    const float* W1 = (const float*)d_in[1];
    const float* b1 = (const float*)d_in[2];
    const float* W2 = (const float*)d_in[3];
    const float* b2 = (const float*)d_in[4];
    const float* Wc = (const float*)d_in[5];
    const float* bc = (const float*)d_in[6];
    const float* wbern = (const float*)d_in[7];
    const int* src = (const int*)d_in[8];
    const int* dst = (const int*)d_in[9];

    const int N = in_sizes[0] / FIN;   // 100000
    const int E = in_sizes[8];         // 1600000
    const int B = (N + 127) >> 7;      // 782 buckets

    // workspace layout
    char* p = (char*)d_ws;
    size_t Np = ((size_t)N + 255) & ~(size_t)255;
    size_t N32 = (size_t)N * HD;
    int* gcursor   = (int*)p;              p += ((size_t)BMAX) * 4;
    int* row_start = (int*)p;              p += Np * 4;
    int* degA      = (int*)p;              p += Np * 4;
    float* dinv    = (float*)p;            p += Np * 4;
    unsigned int* bucket_buf = (unsigned int*)p;  p += (size_t)B * CAP * 4;  // becomes col[]
    float* h   = (float*)p;                p += N32 * 4;
    float* s0  = (float*)p;                p += N32 * 4;
    float* t1  = (float*)p;                p += N32 * 4;
    u32x4* hs  = (u32x4*)p;                p += N32 * 2;   // bf16 table, 64B/row
    u32x4* f1s = (u32x4*)p;                p += N32 * 2;

    int bN = (N + 255) / 256;
    int bG = ((N * 8) + 255) / 256;
    int nTiles = (E + TILE - 1) / TILE;

    init_kernel<<<(B + 255) / 256, 256, 0, stream>>>(gcursor, B);
    partition_kernel<<<nTiles, 256, 0, stream>>>(src, dst, gcursor, bucket_buf, E);
    bucket_csr_kernel<<<B, 256, 0, stream>>>(bucket_buf, gcursor, row_start, degA, dinv, N);

    mlp_kernel<<<bN, 256, 0, stream>>>(feature, W1, b1, W2, b2, dinv, h, hs, N);

    const int* col = (const int*)bucket_buf;
    gather1_kernel<<<bG, 256, 0, stream>>>(h, hs, dinv, row_start, degA, col, s0, f1s, N);
    gather2_kernel<<<bG, 256, 0, stream>>>(f1s, row_start, degA, col, t1, N);

    final_kernel<<<bN, 256, 0, stream>>>(h, s0, t1, dinv, W2, b2, Wc, bc,
                                         wbern, (float*)d_out, N);
}